// Round 1
// baseline (157.516 us; speedup 1.0000x reference)
//
#include <hip/hip_runtime.h>

// CAM_43344809951340: per-sample outer-product tanh attention.
// H_a[i] = 0.1*relu( sum_j tanh(f1_i * av_j * S) * Wca_j + f1_i )
// H_v[i] = 0.1*relu( sum_j tanh(f2_i * av_j * S) * Wcv_j + f2_i )
// out[b, 0:64] = [H_a, H_v]
//
// tanh(x) = 1 - 2/(1 + e^{2x}); e^{2x} = exp2(x * 2*log2(e)).
// Fold SCALE*2*log2(e) into the per-sample av vector; fold -2*W into the
// accumulate; hoist sum(W) out of the loop.
// Per element: v_mul, v_exp_f32, v_add, v_rcp_f32, v_fma  (2 trans + 3 full).

__global__ __launch_bounds__(256) void cam_kernel(
    const float* __restrict__ f1,
    const float* __restrict__ f2,
    const float* __restrict__ Wca,
    const float* __restrict__ Wcv,
    float* __restrict__ out,
    int B)
{
    // SCALE * 2*log2(e) = 0.125 * 2.885390081777927
    constexpr float C = 0.3606737602222409f;

    __shared__ __align__(16) float s_wm2[2][64];   // -2*W rows (0=ca, 1=cv)
    __shared__ float s_wsum[2];                    // sum(W) per row
    __shared__ __align__(16) float s_avs[4][64];   // per-wave scaled av

    const int tid  = threadIdx.x;
    const int lane = tid & 63;
    const int wid  = tid >> 6;

    // ---- one-time per-block prep: -2*W rows + row sums (waves 0 and 1) ----
    if (tid < 128) {
        const int r = tid >> 6;                    // 0: W_ca, 1: W_cv
        const float w = (r ? Wcv : Wca)[lane];
        s_wm2[r][lane] = -2.0f * w;
        float s = w;
        #pragma unroll
        for (int off = 32; off > 0; off >>= 1)
            s += __shfl_xor(s, off, 64);
        if (lane == 0) s_wsum[r] = s;
    }
    __syncthreads();

    const int sel = lane >> 5;                     // 0: audio half, 1: visual half
    const float wsum = s_wsum[sel];
    const float* __restrict__ wm2p = s_wm2[sel];
    float* __restrict__ avp = s_avs[wid];
    const float* __restrict__ fbase = sel ? f2 : f1;
    const int col = lane & 31;

    const int gw     = (blockIdx.x * 256 + tid) >> 6;
    const int stride = (gridDim.x * 256) >> 6;

    for (int b = gw; b < B; b += stride) {
        // lane's own operand; also IS av[lane] for this sample
        const float x = fbase[b * 32 + col];
        avp[lane] = x * C;
        // intra-wave LDS RAW: drain the write before cross-lane reads
        asm volatile("s_waitcnt lgkmcnt(0)" ::: "memory");
        __builtin_amdgcn_sched_barrier(0);

        float acc0 = 0.0f, acc1 = 0.0f, acc2 = 0.0f, acc3 = 0.0f;
        #pragma unroll
        for (int j = 0; j < 64; j += 4) {
            const float4 a4 = *reinterpret_cast<const float4*>(avp + j);
            const float4 w4 = *reinterpret_cast<const float4*>(wm2p + j);
            acc0 = fmaf(__builtin_amdgcn_rcpf(1.0f + __builtin_amdgcn_exp2f(x * a4.x)), w4.x, acc0);
            acc1 = fmaf(__builtin_amdgcn_rcpf(1.0f + __builtin_amdgcn_exp2f(x * a4.y)), w4.y, acc1);
            acc2 = fmaf(__builtin_amdgcn_rcpf(1.0f + __builtin_amdgcn_exp2f(x * a4.z)), w4.z, acc2);
            acc3 = fmaf(__builtin_amdgcn_rcpf(1.0f + __builtin_amdgcn_exp2f(x * a4.w)), w4.w, acc3);
        }
        float h = wsum + ((acc0 + acc1) + (acc2 + acc3)) + x;
        h = fmaxf(h, 0.0f) * 0.1f;
        out[b * 64 + lane] = h;
    }
}

extern "C" void kernel_launch(void* const* d_in, const int* in_sizes, int n_in,
                              void* d_out, int out_size, void* d_ws, size_t ws_size,
                              hipStream_t stream) {
    const float* f1  = (const float*)d_in[0];
    const float* f2  = (const float*)d_in[1];
    const float* Wca = (const float*)d_in[2];
    const float* Wcv = (const float*)d_in[3];
    float* out = (float*)d_out;

    const int B = in_sizes[0] / 32;
    int blocks = (B + 3) / 4;           // 4 waves/block, 1 sample/wave minimum
    if (blocks > 2048) blocks = 2048;   // full occupancy; grid-stride the rest
    if (blocks < 1) blocks = 1;

    cam_kernel<<<blocks, 256, 0, stream>>>(f1, f2, Wca, Wcv, out, B);
}

// Round 2
// 148.067 us; speedup vs baseline: 1.0638x; 1.0638x over previous
//
#include <hip/hip_runtime.h>

// CAM_43344809951340: per-sample outer-product tanh attention, exploiting
// the symmetry T[i][j] = tanh(S*av_i*av_j) = T[j][i].
//
// tanh(u) = 1 - 2/(1+e^{2u}); fold 2*SCALE*log2(e) into scaled av, fold -2W
// into the accumulate, hoist sum(W).
//
// Diagonal walk: step k (0..32), lane r computes p_{r,(r+k)%64}. For
// k=1..31 the mirror p_{r,(r-k)%64} == p_{(r-k)%64, r} is pulled from lane
// (r-k) via ds_bpermute -- halves the transcendental work (4096 -> 2112
// tanh evals per sample). av and -2W rows are duplicated to [128] in LDS so
// every rotated read is a single ds_read_b32 with an immediate offset.

__global__ __launch_bounds__(256) void cam_kernel(
    const float* __restrict__ f1,
    const float* __restrict__ f2,
    const float* __restrict__ Wca,
    const float* __restrict__ Wcv,
    float* __restrict__ out,
    int B)
{
    // 2 * SCALE * log2(e) = 0.25 * 1.4426950408889634
    constexpr float C = 0.3606737602222409f;

    __shared__ float s_w2d[2][128];                // -2*W rows, duplicated
    __shared__ float s_wsum[2];                    // sum(W) per row
    __shared__ __align__(16) float s_avd[4][128];  // per-wave scaled av, duplicated

    const int tid  = threadIdx.x;
    const int lane = tid & 63;
    const int wid  = tid >> 6;

    {   // fill duplicated -2W rows (all 256 threads)
        const int r = tid >> 7;                    // 0: W_ca, 1: W_cv
        const int c = tid & 127;
        const float w = (r ? Wcv : Wca)[c & 63];
        s_w2d[r][c] = -2.0f * w;
    }
    if (tid < 128) {                               // row sums (waves 0,1)
        const int r = wid;
        float s = (r ? Wcv : Wca)[lane];
        #pragma unroll
        for (int off = 32; off > 0; off >>= 1) s += __shfl_xor(s, off, 64);
        if (lane == 0) s_wsum[r] = s;
    }
    __syncthreads();

    const int sel = lane >> 5;                     // 0: audio half, 1: visual half
    const float wsum = s_wsum[sel];
    const float* __restrict__ w2base = &s_w2d[sel][lane];
    float* __restrict__ avw = s_avd[wid];
    const float* __restrict__ avbase = &avw[lane];
    const float* __restrict__ fbase = sel ? f2 : f1;
    const int col = lane & 31;
    const int lane4 = lane << 2;

    const int gw     = (blockIdx.x * 256 + tid) >> 6;
    const int stride = (gridDim.x * 256) >> 6;

    int b = gw;
    if (b >= B) return;                            // wave-uniform
    float x = fbase[b * 32 + col];

    while (b < B) {
        const int bn = b + stride;
        float xn = 0.0f;
        if (bn < B) xn = fbase[bn * 32 + col];     // prefetch next sample

        const float xc = x * C;
        avw[lane]      = xc;                       // duplicated store
        avw[lane + 64] = xc;
        // wave-private LDS rows: drain writes before cross-lane reads
        asm volatile("s_waitcnt lgkmcnt(0)" ::: "memory");
        __builtin_amdgcn_sched_barrier(0);

        float accA, accB = 0.0f, accC = 0.0f, accD = 0.0f;
        {   // k = 0 diagonal: av[lane] == xc, no LDS read
            const float p = __builtin_amdgcn_rcpf(1.0f + __builtin_amdgcn_exp2f(x * xc));
            accA = p * w2base[0];
        }
        int idx = lane4;                           // bpermute byte index, recurrence
        #pragma unroll
        for (int k = 1; k < 32; ++k) {
            idx = (idx - 4) & 252;                 // ((lane-k)&63)<<2
            const float a = avbase[k];             // ds_read imm offset
            const float p = __builtin_amdgcn_rcpf(1.0f + __builtin_amdgcn_exp2f(x * a));
            if (k & 1) accB = fmaf(p, w2base[k], accB);
            else       accA = fmaf(p, w2base[k], accA);
            const float q = __int_as_float(
                __builtin_amdgcn_ds_bpermute(idx, __float_as_int(p)));
            if (k & 1) accC = fmaf(q, w2base[64 - k], accC);
            else       accD = fmaf(q, w2base[64 - k], accD);
        }
        {   // k = 32: lane r and lane r+32 each compute their own copy
            const float a = avbase[32];
            const float p = __builtin_amdgcn_rcpf(1.0f + __builtin_amdgcn_exp2f(x * a));
            accD = fmaf(p, w2base[32], accD);
        }

        float h = wsum + x + ((accA + accB) + (accC + accD));
        h = fmaxf(h, 0.0f) * 0.1f;
        out[b * 64 + lane] = h;

        b = bn;
        x = xn;
    }
}

extern "C" void kernel_launch(void* const* d_in, const int* in_sizes, int n_in,
                              void* d_out, int out_size, void* d_ws, size_t ws_size,
                              hipStream_t stream) {
    const float* f1  = (const float*)d_in[0];
    const float* f2  = (const float*)d_in[1];
    const float* Wca = (const float*)d_in[2];
    const float* Wcv = (const float*)d_in[3];
    float* out = (float*)d_out;

    const int B = in_sizes[0] / 32;
    int blocks = (B + 3) / 4;           // 4 waves/block, 1 sample/wave minimum
    if (blocks > 2048) blocks = 2048;   // 8 waves/SIMD; grid-stride the rest
    if (blocks < 1) blocks = 1;

    cam_kernel<<<blocks, 256, 0, stream>>>(f1, f2, Wca, Wcv, out, B);
}